// Round 17
// baseline (602.258 us; speedup 1.0000x reference)
//
#include <hip/hip_runtime.h>
#include <math.h>

#define NN 100000
#define NE 1000000
#define H 64
#define EB 128        // edges per msg block
#define MBT 256       // msg block threads (4 waves; each wave does 32 edges)
#define MSTRIDE 130   // ushorts per channel row in msg LDS (128 edges + 2 pad)

typedef _Float16 f16x8 __attribute__((ext_vector_type(8)));
typedef _Float16 f16x2 __attribute__((ext_vector_type(2)));
typedef float f32x4  __attribute__((ext_vector_type(4)));

static __device__ __forceinline__ float relu_(float x){ return fmaxf(x, 0.0f); }

static __device__ __forceinline__ unsigned short f2h_(float f){
  union { _Float16 h; unsigned short u; } x; x.h = (_Float16)f; return x.u;
}
static __device__ __forceinline__ float h2f_(unsigned short u){
  union { unsigned short u; _Float16 h; } x; x.u = u; return (float)x.h;
}
static __device__ __forceinline__ unsigned int pkh_(float lo, float hi){
  union { f16x2 v; unsigned int u; } x;
  x.v[0] = (_Float16)lo; x.v[1] = (_Float16)hi;
  return x.u;
}
// packed fp16: relu(a + b) on 2 lanes (lowers to v_pk_add_f16 + v_pk_max_f16)
static __device__ __forceinline__ unsigned int addrelu2_(unsigned int a, unsigned int b){
  union { unsigned int u; f16x2 v; } x, y, r;
  x.u = a; y.u = b;
  f16x2 s = x.v + y.v;
  _Float16 z = (_Float16)0.0f;
  r.v[0] = (s[0] > z) ? s[0] : z;
  r.v[1] = (s[1] > z) ? s[1] : z;
  return r.u;
}
// packed fp16 multiply by broadcast scale (v_pk_mul_f16)
static __device__ __forceinline__ unsigned int mulpk_(unsigned int a, f16x2 s){
  union { unsigned int u; f16x2 v; } x;
  x.u = a; x.v = x.v * s;
  return x.u;
}
static __device__ __forceinline__ void fma32(float* o, float a, const float* wr){
  #pragma unroll
  for (int j=0;j<32;j++) o[j] = fmaf(a, wr[j], o[j]);
}

// ---------------- fused encoder: hbf(fp16) = relu(relu(x@w1+b1)@w2+b2) ----------------
__global__ __launch_bounds__(256, 2) void enc_full_kernel(
    const float* __restrict__ x,
    const float* __restrict__ w1, const float* __restrict__ b1,
    const float* __restrict__ w2, const float* __restrict__ b2,
    unsigned short* __restrict__ hbf)
{
  int v = blockIdx.x*256 + threadIdx.x;
  if (v >= NN) return;
  float in0[5];
  #pragma unroll
  for (int k=0;k<5;k++) in0[k] = x[(size_t)v*5 + k];
  float t[64];
  #pragma unroll
  for (int j=0;j<64;j++) t[j] = b1[j];
  #pragma unroll
  for (int k=0;k<5;k++){
    #pragma unroll
    for (int j=0;j<64;j++) t[j] = fmaf(in0[k], w1[k*H+j], t[j]);
  }
  #pragma unroll
  for (int j=0;j<64;j++) t[j] = relu_(t[j]);

  #pragma unroll 1
  for (int half=0; half<2; half++){
    float o[32];
    #pragma unroll
    for (int j=0;j<32;j++) o[j] = b2[half*32 + j];
    #pragma unroll 4
    for (int k=0;k<64;k++) fma32(o, t[k], w2 + k*H + half*32);
    unsigned int u[16];
    #pragma unroll
    for (int j=0;j<16;j++) u[j] = pkh_(relu_(o[2*j]), relu_(o[2*j+1]));
    uint4* dp = (uint4*)(hbf + (size_t)v*H + half*32);
    #pragma unroll
    for (int j=0;j<4;j++) dp[j] = *(uint4*)&u[4*j];
  }
}

// ---------------- in-degree counts + per-edge rank ----------------
__global__ __launch_bounds__(256) void rank_kernel(const int* __restrict__ dst,
                                                   int* __restrict__ counts,
                                                   int* __restrict__ rank)
{
  int e = blockIdx.x*256 + threadIdx.x;
  if (e < NE) rank[e] = atomicAdd(&counts[dst[e]], 1);
}

// ---------------- scan phase 1 ----------------
__global__ __launch_bounds__(1024) void scan1_kernel(const int* __restrict__ counts,
                                                     int* __restrict__ row_excl,
                                                     int* __restrict__ part)
{
  __shared__ int buf[1024];
  int tid = threadIdx.x;
  int i = blockIdx.x*1024 + tid;
  int v = (i < NN) ? counts[i] : 0;
  buf[tid] = v;
  __syncthreads();
  for (int off=1; off<1024; off<<=1){
    int t = (tid >= off) ? buf[tid-off] : 0;
    __syncthreads();
    buf[tid] += t;
    __syncthreads();
  }
  if (i < NN) row_excl[i] = buf[tid] - v;
  if (tid == 1023) part[blockIdx.x] = buf[1023];
}

// ---------------- scan phase 2 ----------------
__global__ __launch_bounds__(128) void scan2_kernel(int* __restrict__ part, int nparts)
{
  __shared__ int buf[128];
  int tid = threadIdx.x;
  int v = (tid < nparts) ? part[tid] : 0;
  buf[tid] = v;
  __syncthreads();
  for (int off=1; off<128; off<<=1){
    int t = (tid >= off) ? buf[tid-off] : 0;
    __syncthreads();
    buf[tid] += t;
    __syncthreads();
  }
  if (tid < nparts) part[tid] = buf[tid] - v;
}

// ---------------- fill sorted src (no atomics; rank precomputed) ----------------
__global__ __launch_bounds__(256) void fill_kernel(
    const int* __restrict__ src, const int* __restrict__ dst,
    const int* __restrict__ row_excl, const int* __restrict__ part,
    const int* __restrict__ rank, int* __restrict__ ssrc)
{
  int e = blockIdx.x*256 + threadIdx.x;
  if (e >= NE) return;
  int d = dst[e];
  int p = row_excl[d] + part[d >> 10] + rank[e];
  ssrc[p] = src[e];
}

// ---------------- fill sorted dst coalesced from CSR ranges ----------------
__global__ __launch_bounds__(256) void dstfill_kernel(
    const int* __restrict__ counts, const int* __restrict__ row_excl,
    const int* __restrict__ part, int* __restrict__ sdst)
{
  int v = blockIdx.x*256 + threadIdx.x;
  if (v >= NN) return;
  int b = row_excl[v] + part[v >> 10];
  int cnt = counts[v];
  for (int i=0;i<cnt;i++) sdst[b+i] = v;
}

// ---------------- preswizzle ALL weights to fp16 MFMA B-fragment order -------------
// frag index within a K x N weight: idx = ((kb*4+quad)*N + col)*8 + j,  k = kb*32+quad*8+j
// layout (ushort elems): [0,24576) uw1p | [24576,36864) uw2p |
// [36864,61440) pprojp | [61440,65536) ow1p | [65536,77824) msgw2p   (all fp16)
__global__ __launch_bounds__(256) void prep_all_kernel(
    const float* __restrict__ uw1, const float* __restrict__ uw2,
    const float* __restrict__ mw1, const float* __restrict__ mw2,
    const float* __restrict__ ow1, unsigned short* __restrict__ wp)
{
  int i = blockIdx.x*256 + threadIdx.x;
  if (i >= 77824) return;
  float val;
  if (i < 24576){
    int l = i / 8192, r = i & 8191;
    int j = r & 7, col = (r >> 3) & 63, g = r >> 9;
    int k = (g >> 2)*32 + (g & 3)*8 + j;
    val = uw1[(size_t)l*8192 + k*64 + col];
  } else if (i < 36864){
    int t = i - 24576; int l = t / 4096, r = t & 4095;
    int j = r & 7, col = (r >> 3) & 63, g = r >> 9;
    int k = (g >> 2)*32 + (g & 3)*8 + j;
    val = uw2[(size_t)l*4096 + k*64 + col];
  } else if (i < 61440){
    int t = i - 36864; int l = t / 8192, r = t & 8191;
    int j = r & 7, col = (r >> 3) & 127, g = r >> 10;
    int k = (g >> 2)*32 + (g & 3)*8 + j;
    val = mw1[(size_t)l*8192 + ((col >> 6)*64 + k)*64 + (col & 63)];
  } else if (i < 65536){
    int r = i - 61440;
    int j = r & 7, col = (r >> 3) & 63, g = r >> 9;
    int k = (g >> 2)*32 + (g & 3)*8 + j;
    val = ow1[k*64 + col];
  } else {
    int t = i - 65536; int l = t / 4096, r = t & 4095;
    int j = r & 7, col = (r >> 3) & 63, g = r >> 9;
    int k = (g >> 2)*32 + (g & 3)*8 + j;
    val = mw2[(size_t)l*4096 + k*64 + col];
  }
  wp[i] = f2h_(val);
}

// ---------------- MFMA message kernel v11: v10 + __launch_bounds__(MBT, 8) ----------
// Single-variable probe: raise declared occupancy target 4 -> 8 waves/SIMD.
__global__ __launch_bounds__(MBT, 8) void msg_mfma_kernel(
    const unsigned short* __restrict__ P,
    const unsigned short* __restrict__ w2p,
    const float* __restrict__ b2,
    const int* __restrict__ ssrc, const int* __restrict__ sdst,
    unsigned short* __restrict__ aggh,
    float* __restrict__ bval, int* __restrict__ bdst)
{
  __shared__ unsigned short mlds[64*MSTRIDE];
  __shared__ int2 sdl[EB];
  const int tid  = threadIdx.x;
  const int wave = tid >> 6, lane = tid & 63, quad = lane >> 4, c = lane & 15;

  // XCD-contiguous swizzle
  int bid = blockIdx.x;
  int ng = gridDim.x >> 3;
  int lb = (bid < (ng << 3)) ? ((bid & 7)*ng + (bid >> 3)) : bid;
  const int base = lb*EB;

  if (tid < EB){
    int p = base + tid;
    int sv = 0, dv = -1;
    if (p < NE){ sv = ssrc[p]; dv = sdst[p]; }
    sdl[tid] = make_int2(sv, dv);
  }

  // B fragments (fp16) + bias
  f16x8 bfr[4][2];
  #pragma unroll
  for (int n=0;n<4;n++)
    #pragma unroll
    for (int kb=0;kb<2;kb++)
      bfr[n][kb] = *(const f16x8*)(w2p + (((kb*4 + quad)*64 + n*16 + c) << 3));
  float bv[4];
  #pragma unroll
  for (int n=0;n<4;n++) bv[n] = b2[n*16 + c];

  __syncthreads();

  const int ebase = wave*32;
  #pragma unroll
  for (int t=0;t<2;t++){
    int2 sd = sdl[ebase + t*16 + c];
    int s = sd.x;
    int d = sd.y < 0 ? 0 : sd.y;
    const unsigned short* p1 = P + (size_t)s*128 + quad*8;
    const unsigned short* p2 = P + (size_t)d*128 + 64 + quad*8;
    f16x8 af[2];
    #pragma unroll
    for (int kb=0;kb<2;kb++){
      uint4 u1 = *(const uint4*)(p1 + kb*32);
      uint4 u2 = *(const uint4*)(p2 + kb*32);
      union { unsigned int u[4]; f16x8 v; } A;
      A.u[0] = addrelu2_(u1.x, u2.x);
      A.u[1] = addrelu2_(u1.y, u2.y);
      A.u[2] = addrelu2_(u1.z, u2.z);
      A.u[3] = addrelu2_(u1.w, u2.w);
      af[kb] = A.v;
    }

    f32x4 acc4[4];
    #pragma unroll
    for (int n=0;n<4;n++) acc4[n] = (f32x4){0.f, 0.f, 0.f, 0.f};
    #pragma unroll
    for (int n=0;n<4;n++){
      acc4[n] = __builtin_amdgcn_mfma_f32_16x16x32_f16(af[0], bfr[n][0], acc4[n], 0, 0, 0);
      acc4[n] = __builtin_amdgcn_mfma_f32_16x16x32_f16(af[1], bfr[n][1], acc4[n], 0, 0, 0);
    }

    int e0 = ebase + t*16 + quad*4;
    #pragma unroll
    for (int n=0;n<4;n++){
      int ch = n*16 + c;
      float v0 = relu_(acc4[n][0] + bv[n]);
      float v1 = relu_(acc4[n][1] + bv[n]);
      float v2 = relu_(acc4[n][2] + bv[n]);
      float v3 = relu_(acc4[n][3] + bv[n]);
      *(unsigned int*)&mlds[ch*MSTRIDE + e0]     = pkh_(v0, v1);
      *(unsigned int*)&mlds[ch*MSTRIDE + e0 + 2] = pkh_(v2, v3);
    }
  }
  __syncthreads();

  // ---- block-wide peek-ahead segmented reduce (single owner per run) ----
  // wave g owns runs STARTING in [g*32,(g+1)*32); SIMPLE accumulation walk.
  {
    const int g = wave;
    const int ch = lane;
    int r = g*32;
    if (g > 0){
      int prev = sdl[r-1].y;
      while (r < EB && sdl[r].y == prev) r++;
    }
    while (r < EB){
      int runstart = r;
      if (runstart >= (g+1)*32) break;
      int cur = sdl[r].y;
      float s2 = 0.f;
      while (r < EB && sdl[r].y == cur){
        s2 += h2f_(mlds[ch*MSTRIDE + r]);
        r++;
      }
      if (cur >= 0){
        bool headB = (runstart == 0);
        bool tailB = (r == EB);
        if (headB){
          bval[(size_t)(2*lb)*64 + ch] = s2;
          if (ch == 0) bdst[2*lb] = cur;
          if (tailB){
            bval[(size_t)(2*lb+1)*64 + ch] = 0.f;   // contiguity filler
            if (ch == 0) bdst[2*lb+1] = cur;
          }
        } else if (tailB){
          bval[(size_t)(2*lb+1)*64 + ch] = s2;
          if (ch == 0) bdst[2*lb+1] = cur;
        } else {
          aggh[(size_t)cur*H + ch] = f2h_(s2);
        }
      }
    }
  }
}

// ---------------- second-level boundary merge: zero atomics, plain stores ----------
__global__ __launch_bounds__(256) void bnd_fixup_kernel(
    const int* __restrict__ bdst, const float* __restrict__ bval,
    unsigned short* __restrict__ aggh, int nbnd)
{
  const int wave = threadIdx.x >> 6, ch = threadIdx.x & 63;
  int g = blockIdx.x*4 + wave;
  int r0 = g*64;
  if (r0 >= nbnd) return;
  int r = r0;
  if (r0 > 0){
    int prev = bdst[r0-1];
    while (r < nbnd && bdst[r] == prev) r++;
  }
  int rlim = r0 + 64;
  while (r < nbnd){
    int runstart = r;
    if (runstart >= rlim) break;
    int cur = bdst[r];
    float s = 0.f;
    while (r < nbnd && bdst[r] == cur){
      s += bval[(size_t)r*64 + ch];
      r++;
    }
    if (cur >= 0) aggh[(size_t)cur*H + ch] = f2h_(s);
  }
}

// ---------------- fused node-side layer kernel (fp16 MFMA, fp16 agg in) -------------
// mode 0 (l=0,1): h' = relu-MLP2([h||agg/deg]) -> hout(fp16) ; P_next = h'@W3 (+b3 top) -> Pout
// mode 1 (l=2):   h' as above; out = 2pi*sigmoid(relu(h'@ow1+b3)@ow2+ob2) -> outp
// mode 2 (pproj only): P = hbf@W3 (+b3 top) -> Pout
// Zero-degree nodes: agg never written (no memset) -> masked via invd=0.
__global__ __launch_bounds__(256) void node_fused_kernel(
    const unsigned short* __restrict__ hbf,
    const unsigned short* __restrict__ aggh, const int* __restrict__ counts,
    const unsigned short* __restrict__ uw1p, const float* __restrict__ ub1,
    const unsigned short* __restrict__ uw2p, const float* __restrict__ ub2,
    const unsigned short* __restrict__ w3p,  const float* __restrict__ b3,
    const float* __restrict__ ow2, const float* __restrict__ ob2,
    unsigned short* __restrict__ hout,
    unsigned short* __restrict__ Pout,
    float* __restrict__ outp,
    int mode)
{
  __shared__ __align__(16) unsigned short act[64*72];
  __shared__ __align__(16) unsigned short pst[64*136];
  const int tid = threadIdx.x, wave = tid >> 6, lane = tid & 63;
  const int quad = lane >> 4, c = lane & 15;
  const int vb = blockIdx.x*64;
  int myv = vb + wave*16 + c;
  int vld = myv < NN ? myv : NN-1;

  if (mode != 2){
    int cntv = counts[vld];
    float invf = (cntv > 0) ? (1.0f / (float)cntv) : 0.0f;   // masks unwritten agg
    f16x2 invd2; invd2[0] = (_Float16)invf; invd2[1] = (_Float16)invf;
    f16x8 a1[4];
    a1[0] = *(const f16x8*)(hbf + (size_t)vld*H + quad*8);
    a1[1] = *(const f16x8*)(hbf + (size_t)vld*H + 32 + quad*8);
    #pragma unroll
    for (int kb2=0; kb2<2; kb2++){
      uint4 u = *(const uint4*)(aggh + (size_t)vld*H + kb2*32 + quad*8);
      union { unsigned int u[4]; f16x8 v; } A;
      A.u[0] = mulpk_(u.x, invd2);
      A.u[1] = mulpk_(u.y, invd2);
      A.u[2] = mulpk_(u.z, invd2);
      A.u[3] = mulpk_(u.w, invd2);
      a1[2+kb2] = A.v;
    }
    f32x4 acc1[4];
    #pragma unroll
    for (int n=0;n<4;n++) acc1[n] = (f32x4){0.f,0.f,0.f,0.f};
    #pragma unroll
    for (int n=0;n<4;n++){
      #pragma unroll
      for (int kb=0;kb<4;kb++){
        f16x8 b = *(const f16x8*)(uw1p + (((kb*4 + quad)*64 + n*16 + c) << 3));
        acc1[n] = __builtin_amdgcn_mfma_f32_16x16x32_f16(a1[kb], b, acc1[n], 0, 0, 0);
      }
    }
    #pragma unroll
    for (int n=0;n<4;n++){
      float bb = ub1[n*16 + c];
      #pragma unroll
      for (int r=0;r<4;r++)
        act[(wave*16 + quad*4 + r)*72 + n*16 + c] = f2h_(relu_(acc1[n][r] + bb));
    }

    f16x8 a2[2];
    a2[0] = *(const f16x8*)(act + (wave*16 + c)*72 + quad*8);
    a2[1] = *(const f16x8*)(act + (wave*16 + c)*72 + 32 + quad*8);
    f32x4 acc2[4];
    #pragma unroll
    for (int n=0;n<4;n++) acc2[n] = (f32x4){0.f,0.f,0.f,0.f};
    #pragma unroll
    for (int n=0;n<4;n++){
      #pragma unroll
      for (int kb=0;kb<2;kb++){
        f16x8 b = *(const f16x8*)(uw2p + (((kb*4 + quad)*64 + n*16 + c) << 3));
        acc2[n] = __builtin_amdgcn_mfma_f32_16x16x32_f16(a2[kb], b, acc2[n], 0, 0, 0);
      }
    }
    #pragma unroll
    for (int n=0;n<4;n++){
      float bb = ub2[n*16 + c];
      #pragma unroll
      for (int r=0;r<4;r++)
        act[(wave*16 + quad*4 + r)*72 + n*16 + c] = f2h_(relu_(acc2[n][r] + bb));
    }
  }

  f16x8 a3[2];
  if (mode == 2){
    a3[0] = *(const f16x8*)(hbf + (size_t)vld*H + quad*8);
    a3[1] = *(const f16x8*)(hbf + (size_t)vld*H + 32 + quad*8);
  } else {
    a3[0] = *(const f16x8*)(act + (wave*16 + c)*72 + quad*8);
    a3[1] = *(const f16x8*)(act + (wave*16 + c)*72 + 32 + quad*8);
  }

  if (mode == 1){
    f32x4 acc3[4];
    #pragma unroll
    for (int n=0;n<4;n++) acc3[n] = (f32x4){0.f,0.f,0.f,0.f};
    #pragma unroll
    for (int n=0;n<4;n++){
      #pragma unroll
      for (int kb=0;kb<2;kb++){
        f16x8 b = *(const f16x8*)(w3p + (((kb*4 + quad)*64 + n*16 + c) << 3));
        acc3[n] = __builtin_amdgcn_mfma_f32_16x16x32_f16(a3[kb], b, acc3[n], 0, 0, 0);
      }
    }
    #pragma unroll
    for (int n=0;n<4;n++){
      float bb = b3[n*16 + c];
      #pragma unroll
      for (int r=0;r<4;r++)
        act[(wave*16 + quad*4 + r)*72 + n*16 + c] = f2h_(relu_(acc3[n][r] + bb));
    }
  } else {
    f32x4 acc3[8];
    #pragma unroll
    for (int n=0;n<8;n++) acc3[n] = (f32x4){0.f,0.f,0.f,0.f};
    #pragma unroll
    for (int n=0;n<8;n++){
      #pragma unroll
      for (int kb=0;kb<2;kb++){
        f16x8 b = *(const f16x8*)(w3p + (((kb*4 + quad)*128 + n*16 + c) << 3));
        acc3[n] = __builtin_amdgcn_mfma_f32_16x16x32_f16(a3[kb], b, acc3[n], 0, 0, 0);
      }
    }
    #pragma unroll
    for (int n=0;n<8;n++){
      int ch = n*16 + c;
      float bb = (ch >= 64) ? b3[ch - 64] : 0.0f;
      #pragma unroll
      for (int r=0;r<4;r++)
        pst[(wave*16 + quad*4 + r)*136 + ch] = f2h_(acc3[n][r] + bb);
    }
  }

  __syncthreads();

  if (mode == 0){
    #pragma unroll
    for (int rr=0; rr<2; rr++){
      int idx = tid + rr*256;
      int node = idx >> 3, ko = (idx & 7)*8;
      int v = vb + node;
      if (v < NN) *(uint4*)(hout + (size_t)v*H + ko) = *(const uint4*)(act + node*72 + ko);
    }
  }
  if (mode == 0 || mode == 2){
    #pragma unroll
    for (int rr=0; rr<4; rr++){
      int idx = tid + rr*256;
      int node = idx >> 4, cho = (idx & 15)*8;
      int v = vb + node;
      if (v < NN) *(uint4*)(Pout + (size_t)v*128 + cho) = *(const uint4*)(pst + node*136 + cho);
    }
  }
  if (mode == 1){
    if (tid < 192){
      int node = tid / 3;
      int v = vb + node;
      if (v < NN){
        int cm = tid - node*3;
        float s = ob2[cm];
        #pragma unroll 8
        for (int k=0;k<64;k++)
          s = fmaf(h2f_(act[node*72 + k]), ow2[k*3 + cm], s);
        outp[(size_t)v*3 + cm] = 6.283185307179586f / (1.0f + __expf(-s));
      }
    }
  }
}

// ================= legacy fallback kernels (known correct; small ws) =================
__global__ __launch_bounds__(256) void enc_kernel_legacy(
    const float* __restrict__ x,
    const float* __restrict__ w1, const float* __restrict__ b1,
    const float* __restrict__ w2, const float* __restrict__ b2,
    float* __restrict__ h)
{
  int v = blockIdx.x*256 + threadIdx.x;
  if (v >= NN) return;
  float in0[5];
  #pragma unroll
  for (int k=0;k<5;k++) in0[k] = x[v*5+k];
  float hid[H];
  #pragma unroll
  for (int j=0;j<H;j++) hid[j] = b1[j];
  #pragma unroll
  for (int k=0;k<5;k++){
    #pragma unroll
    for (int j=0;j<H;j++) hid[j] = fmaf(in0[k], w1[k*H+j], hid[j]);
  }
  float o[H];
  #pragma unroll
  for (int j=0;j<H;j++) o[j] = b2[j];
  #pragma unroll
  for (int k=0;k<H;k++){
    float hk = relu_(hid[k]);
    #pragma unroll
    for (int j=0;j<H;j++) o[j] = fmaf(hk, w2[k*H+j], o[j]);
  }
  float4* hw = (float4*)(h + (size_t)v*H);
  #pragma unroll
  for (int j4=0;j4<H/4;j4++){
    float4 t;
    t.x = relu_(o[4*j4+0]); t.y = relu_(o[4*j4+1]);
    t.z = relu_(o[4*j4+2]); t.w = relu_(o[4*j4+3]);
    hw[j4] = t;
  }
}

__global__ __launch_bounds__(256) void msg_kernel_atomic(
    const float* __restrict__ h,
    const int* __restrict__ src, const int* __restrict__ dst,
    const float* __restrict__ w1, const float* __restrict__ b1,
    const float* __restrict__ w2, const float* __restrict__ b2,
    float* __restrict__ agg)
{
  int e = blockIdx.x*256 + threadIdx.x;
  if (e >= NE) return;
  int s = src[e], d = dst[e];
  const float4* hs = (const float4*)(h + (size_t)s*H);
  const float4* hd = (const float4*)(h + (size_t)d*H);
  float hid[H];
  #pragma unroll
  for (int j=0;j<H;j++) hid[j] = b1[j];
  #pragma unroll 4
  for (int k4=0;k4<16;k4++){
    float4 a = hs[k4];
    const float* wr = w1 + (size_t)(4*k4)*H;
    #pragma unroll
    for (int j=0;j<H;j++) hid[j] = fmaf(a.x, wr[j], hid[j]);
    #pragma unroll
    for (int j=0;j<H;j++) hid[j] = fmaf(a.y, wr[H+j], hid[j]);
    #pragma unroll
    for (int j=0;j<H;j++) hid[j] = fmaf(a.z, wr[2*H+j], hid[j]);
    #pragma unroll
    for (int j=0;j<H;j++) hid[j] = fmaf(a.w, wr[3*H+j], hid[j]);
  }
  #pragma unroll 4
  for (int k4=0;k4<16;k4++){
    float4 a = hd[k4];
    const float* wr = w1 + (size_t)(64 + 4*k4)*H;
    #pragma unroll
    for (int j=0;j<H;j++) hid[j] = fmaf(a.x, wr[j], hid[j]);
    #pragma unroll
    for (int j=0;j<H;j++) hid[j] = fmaf(a.y, wr[H+j], hid[j]);
    #pragma unroll
    for (int j=0;j<H;j++) hid[j] = fmaf(a.z, wr[2*H+j], hid[j]);
    #pragma unroll
    for (int j=0;j<H;j++) hid[j] = fmaf(a.w, wr[3*H+j], hid[j]);
  }
  float o[H];
  #pragma unroll
  for (int j=0;j<H;j++) o[j] = b2[j];
  #pragma unroll
  for (int k=0;k<H;k++){
    float hk = relu_(hid[k]);
    #pragma unroll
    for (int j=0;j<H;j++) o[j] = fmaf(hk, w2[k*H+j], o[j]);
  }
  float* arow = agg + (size_t)d*H;
  #pragma unroll
  for (int j=0;j<H;j++) atomicAdd(arow + j, relu_(o[j]));
}

__global__ __launch_bounds__(256) void div_kernel(float* __restrict__ agg,
                                                  const int* __restrict__ counts)
{
  int i = blockIdx.x*256 + threadIdx.x;
  if (i >= NN*H/4) return;
  int v = i / (H/4);
  float invd = 1.0f / fmaxf((float)counts[v], 1.0f);
  float4* a = (float4*)agg + i;
  float4 t = *a;
  t.x *= invd; t.y *= invd; t.z *= invd; t.w *= invd;
  *a = t;
}

__global__ __launch_bounds__(256) void upd_kernel_legacy(
    float* __restrict__ h, const float* __restrict__ agg,
    const float* __restrict__ w1, const float* __restrict__ b1,
    const float* __restrict__ w2, const float* __restrict__ b2)
{
  int v = blockIdx.x*256 + threadIdx.x;
  if (v >= NN) return;
  const float4* hv = (const float4*)(h + (size_t)v*H);
  const float4* av = (const float4*)(agg + (size_t)v*H);
  float hid[H];
  #pragma unroll
  for (int j=0;j<H;j++) hid[j] = b1[j];
  #pragma unroll 4
  for (int k4=0;k4<16;k4++){
    float4 a = hv[k4];
    const float* wr = w1 + (size_t)(4*k4)*H;
    #pragma unroll
    for (int j=0;j<H;j++) hid[j] = fmaf(a.x, wr[j], hid[j]);
    #pragma unroll
    for (int j=0;j<H;j++) hid[j] = fmaf(a.y, wr[H+j], hid[j]);
    #pragma unroll
    for (int j=0;j<H;j++) hid[j] = fmaf(a.z, wr[2*H+j], hid[j]);
    #pragma unroll
    for (int j=0;j<H;j++) hid[j] = fmaf(a.w, wr[3*H+j], hid[j]);
  }
  #pragma unroll 4
  for (int k4=0;k4<16;k4++){
    float4 a = av[k4];
    const float* wr = w1 + (size_t)(64 + 4*k4)*H;
    #pragma unroll
    for (int j=0;j<H;j++) hid[j] = fmaf(a.x, wr[j], hid[j]);
    #pragma unroll
    for (int j=0;j<H;j++) hid[j] = fmaf(a.y, wr[H+j], hid[j]);
    #pragma unroll
    for (int j=0;j<H;j++) hid[j] = fmaf(a.z, wr[2*H+j], hid[j]);
    #pragma unroll
    for (int j=0;j<H;j++) hid[j] = fmaf(a.w, wr[3*H+j], hid[j]);
  }
  float o[H];
  #pragma unroll
  for (int j=0;j<H;j++) o[j] = b2[j];
  #pragma unroll
  for (int k=0;k<H;k++){
    float hk = relu_(hid[k]);
    #pragma unroll
    for (int j=0;j<H;j++) o[j] = fmaf(hk, w2[k*H+j], o[j]);
  }
  float4* hw = (float4*)(h + (size_t)v*H);
  #pragma unroll
  for (int j4=0;j4<H/4;j4++){
    float4 t;
    t.x = relu_(o[4*j4+0]); t.y = relu_(o[4*j4+1]);
    t.z = relu_(o[4*j4+2]); t.w = relu_(o[4*j4+3]);
    hw[j4] = t;
  }
}

__global__ __launch_bounds__(256) void out_kernel2(
    const float* __restrict__ h,
    const float* __restrict__ w1, const float* __restrict__ b1,
    const float* __restrict__ w2, const float* __restrict__ b2,
    float* __restrict__ out)
{
  int v = blockIdx.x*256 + threadIdx.x;
  if (v >= NN) return;
  const float4* hv = (const float4*)(h + (size_t)v*H);
  float pr[3] = { b2[0], b2[1], b2[2] };
  #pragma unroll 1
  for (int half=0; half<2; half++){
    float o[32];
    #pragma unroll
    for (int j=0;j<32;j++) o[j] = b1[half*32 + j];
    #pragma unroll 4
    for (int k4=0;k4<16;k4++){
      float4 a = hv[k4];
      const float* wr = w1 + (4*k4)*H + half*32;
      fma32(o, a.x, wr); fma32(o, a.y, wr+H); fma32(o, a.z, wr+2*H); fma32(o, a.w, wr+3*H);
    }
    #pragma unroll
    for (int j=0;j<32;j++){
      float hk = relu_(o[j]);
      int k = half*32 + j;
      pr[0] = fmaf(hk, w2[k*3+0], pr[0]);
      pr[1] = fmaf(hk, w2[k*3+1], pr[1]);
      pr[2] = fmaf(hk, w2[k*3+2], pr[2]);
    }
  }
  #pragma unroll
  for (int c=0;c<3;c++)
    out[(size_t)v*3 + c] = 6.283185307179586f / (1.0f + __expf(-pr[c]));
}

// =====================================================================

extern "C" void kernel_launch(void* const* d_in, const int* in_sizes, int n_in,
                              void* d_out, int out_size, void* d_ws, size_t ws_size,
                              hipStream_t stream)
{
  const float* x      = (const float*)d_in[0];
  const int*   ei     = (const int*)  d_in[1];
  const float* enc_w1 = (const float*)d_in[2];
  const float* enc_b1 = (const float*)d_in[3];
  const float* enc_w2 = (const float*)d_in[4];
  const float* enc_b2 = (const float*)d_in[5];
  const float* msg_w1 = (const float*)d_in[6];
  const float* msg_b1 = (const float*)d_in[7];
  const float* msg_w2 = (const float*)d_in[8];
  const float* msg_b2 = (const float*)d_in[9];
  const float* upd_w1 = (const float*)d_in[10];
  const float* upd_b1 = (const float*)d_in[11];
  const float* upd_w2 = (const float*)d_in[12];
  const float* upd_b2 = (const float*)d_in[13];
  const float* out_w1 = (const float*)d_in[14];
  const float* out_b1 = (const float*)d_in[15];
  const float* out_w2 = (const float*)d_in[16];
  const float* out_b2 = (const float*)d_in[17];
  float* out = (float*)d_out;

  const int* srcp = ei;
  const int* dstp = ei + NE;

  const int nodeBlocks  = (NN + 255)/256;
  const int edgeBlocks  = (NE + 255)/256;
  const int msgBlocks   = (NE + EB - 1)/EB;          // 7813
  const int nbnd        = 2*msgBlocks;               // 15626
  const int fixBlocks   = ((nbnd + 63)/64 + 3)/4;    // 62
  const int scanBlocks  = (NN + 1023)/1024;
  const int fusedBlocks = (NN + 63)/64;              // 1563

  // ---- workspace layout ----
  char* wp_ = (char*)d_ws;
  auto take = [&wp_](size_t bytes) -> char* {
    char* r = wp_;
    wp_ += (bytes + 255) & ~(size_t)255;
    return r;
  };
  unsigned short* hbf = (unsigned short*)take((size_t)NN*H*sizeof(unsigned short)); // 12.8 MB fp16
  unsigned short* P   = (unsigned short*)take((size_t)NN*128*sizeof(unsigned short)); // 25.6 MB fp16
  unsigned short* aggh= (unsigned short*)take((size_t)NN*H*sizeof(unsigned short)); // 12.8 MB fp16
  int* counts         = (int*)take((size_t)NN*sizeof(int));
  int* row_excl       = (int*)take((size_t)NN*sizeof(int));
  int* part           = (int*)take(1024);
  int* rank           = (int*)take((size_t)NE*sizeof(int));                        // 4 MB
  int* ssrc           = (int*)take((size_t)NE*sizeof(int));                        // 4 MB
  int* sdst           = (int*)take((size_t)NE*sizeof(int));                        // 4 MB
  float* bval         = (float*)take((size_t)nbnd*64*sizeof(float));               // 4 MB
  int* bdst           = (int*)take((size_t)nbnd*sizeof(int));
  unsigned short* wpz = (unsigned short*)take((size_t)77824*sizeof(unsigned short));
  size_t need = (size_t)(wp_ - (char*)d_ws);

  // preswizzled-weight offsets (ushort elements)
  const size_t UW1 = 0, UW2 = 24576, PPJ = 36864, OW1 = 61440, MW2 = 65536;

  if (ws_size >= need) {
    (void)hipMemsetAsync(counts, 0, NN*sizeof(int), stream);
    (void)hipMemsetAsync(bdst, 0xFF, nbnd*sizeof(int), stream);   // dst = -1 sentinel

    enc_full_kernel<<<nodeBlocks, 256, 0, stream>>>(x, enc_w1, enc_b1, enc_w2, enc_b2, hbf);

    rank_kernel<<<edgeBlocks, 256, 0, stream>>>(dstp, counts, rank);
    scan1_kernel<<<scanBlocks, 1024, 0, stream>>>(counts, row_excl, part);
    scan2_kernel<<<1, 128, 0, stream>>>(part, scanBlocks);
    fill_kernel<<<edgeBlocks, 256, 0, stream>>>(srcp, dstp, row_excl, part, rank, ssrc);
    dstfill_kernel<<<nodeBlocks, 256, 0, stream>>>(counts, row_excl, part, sdst);
    prep_all_kernel<<<(77824 + 255)/256, 256, 0, stream>>>(upd_w1, upd_w2, msg_w1, msg_w2, out_w1, wpz);

    // layer-0 P projection (mode 2)
    node_fused_kernel<<<fusedBlocks, 256, 0, stream>>>(
        hbf, aggh, counts,
        nullptr, nullptr, nullptr, nullptr,
        wpz + PPJ, msg_b1, nullptr, nullptr,
        nullptr, P, nullptr, 2);

    for (int l=0; l<3; l++){
      msg_mfma_kernel<<<msgBlocks, MBT, 0, stream>>>(P, wpz + MW2 + (size_t)l*4096,
          msg_b2 + (size_t)l*H, ssrc, sdst, aggh, bval, bdst);
      bnd_fixup_kernel<<<fixBlocks, 256, 0, stream>>>(bdst, bval, aggh, nbnd);
      if (l < 2){
        node_fused_kernel<<<fusedBlocks, 256, 0, stream>>>(
            hbf, aggh, counts,
            wpz + UW1 + (size_t)l*8192, upd_b1 + (size_t)l*H,
            wpz + UW2 + (size_t)l*4096, upd_b2 + (size_t)l*H,
            wpz + PPJ + (size_t)(l+1)*8192, msg_b1 + (size_t)(l+1)*H,
            nullptr, nullptr,
            hbf, P, nullptr, 0);
      } else {
        node_fused_kernel<<<fusedBlocks, 256, 0, stream>>>(
            hbf, aggh, counts,
            wpz + UW1 + (size_t)l*8192, upd_b1 + (size_t)l*H,
            wpz + UW2 + (size_t)l*4096, upd_b2 + (size_t)l*H,
            wpz + OW1, out_b1,
            out_w2, out_b2,
            nullptr, nullptr, out, 1);
      }
    }
  } else {
    // ======== fallback: legacy atomic path (fits in ~52 MB) ========
    char* fp = (char*)d_ws;
    float* fh   = (float*)fp;  fp += (size_t)NN*H*sizeof(float);
    float* fagg = (float*)fp;  fp += (size_t)NN*H*sizeof(float);
    int* fcnt   = (int*)fp;

    (void)hipMemsetAsync(fcnt, 0, NN*sizeof(int), stream);
    enc_kernel_legacy<<<nodeBlocks, 256, 0, stream>>>(x, enc_w1, enc_b1, enc_w2, enc_b2, fh);
    rank_kernel<<<edgeBlocks, 256, 0, stream>>>(dstp, fcnt, (int*)(fcnt + NN));
    for (int l=0; l<3; l++){
      (void)hipMemsetAsync(fagg, 0, (size_t)NN*H*sizeof(float), stream);
      msg_kernel_atomic<<<edgeBlocks, 256, 0, stream>>>(fh, srcp, dstp,
          msg_w1 + (size_t)l*128*H, msg_b1 + (size_t)l*H,
          msg_w2 + (size_t)l*H*H,   msg_b2 + (size_t)l*H, fagg);
      div_kernel<<<(NN*H/4 + 255)/256, 256, 0, stream>>>(fagg, fcnt);
      upd_kernel_legacy<<<nodeBlocks, 256, 0, stream>>>(fh, fagg,
          upd_w1 + (size_t)l*128*H, upd_b1 + (size_t)l*H,
          upd_w2 + (size_t)l*H*H,   upd_b2 + (size_t)l*H);
    }
    out_kernel2<<<nodeBlocks, 256, 0, stream>>>(fh, out_w1, out_b1, out_w2, out_b2, out);
  }
}

// Round 18
// 510.395 us; speedup vs baseline: 1.1800x; 1.1800x over previous
//
#include <hip/hip_runtime.h>
#include <math.h>

#define NN 100000
#define NE 1000000
#define H 64
#define EB 128        // edges per msg block
#define MBT 256       // msg block threads (4 waves; each wave does 32 edges)
#define MSTRIDE 130   // ushorts per channel row in msg LDS (128 edges + 2 pad)

typedef _Float16 f16x8 __attribute__((ext_vector_type(8)));
typedef _Float16 f16x2 __attribute__((ext_vector_type(2)));
typedef float f32x4  __attribute__((ext_vector_type(4)));

static __device__ __forceinline__ float relu_(float x){ return fmaxf(x, 0.0f); }

static __device__ __forceinline__ unsigned short f2h_(float f){
  union { _Float16 h; unsigned short u; } x; x.h = (_Float16)f; return x.u;
}
static __device__ __forceinline__ float h2f_(unsigned short u){
  union { unsigned short u; _Float16 h; } x; x.u = u; return (float)x.h;
}
static __device__ __forceinline__ unsigned int pkh_(float lo, float hi){
  union { f16x2 v; unsigned int u; } x;
  x.v[0] = (_Float16)lo; x.v[1] = (_Float16)hi;
  return x.u;
}
// packed fp16: relu(a + b) on 2 lanes (lowers to v_pk_add_f16 + v_pk_max_f16)
static __device__ __forceinline__ unsigned int addrelu2_(unsigned int a, unsigned int b){
  union { unsigned int u; f16x2 v; } x, y, r;
  x.u = a; y.u = b;
  f16x2 s = x.v + y.v;
  _Float16 z = (_Float16)0.0f;
  r.v[0] = (s[0] > z) ? s[0] : z;
  r.v[1] = (s[1] > z) ? s[1] : z;
  return r.u;
}
// packed fp16 multiply by broadcast scale (v_pk_mul_f16)
static __device__ __forceinline__ unsigned int mulpk_(unsigned int a, f16x2 s){
  union { unsigned int u; f16x2 v; } x;
  x.u = a; x.v = x.v * s;
  return x.u;
}
static __device__ __forceinline__ void fma32(float* o, float a, const float* wr){
  #pragma unroll
  for (int j=0;j<32;j++) o[j] = fmaf(a, wr[j], o[j]);
}

// ---------------- fused encoder: hbf(fp16) = relu(relu(x@w1+b1)@w2+b2) ----------------
__global__ __launch_bounds__(256, 2) void enc_full_kernel(
    const float* __restrict__ x,
    const float* __restrict__ w1, const float* __restrict__ b1,
    const float* __restrict__ w2, const float* __restrict__ b2,
    unsigned short* __restrict__ hbf)
{
  int v = blockIdx.x*256 + threadIdx.x;
  if (v >= NN) return;
  float in0[5];
  #pragma unroll
  for (int k=0;k<5;k++) in0[k] = x[(size_t)v*5 + k];
  float t[64];
  #pragma unroll
  for (int j=0;j<64;j++) t[j] = b1[j];
  #pragma unroll
  for (int k=0;k<5;k++){
    #pragma unroll
    for (int j=0;j<64;j++) t[j] = fmaf(in0[k], w1[k*H+j], t[j]);
  }
  #pragma unroll
  for (int j=0;j<64;j++) t[j] = relu_(t[j]);

  #pragma unroll 1
  for (int half=0; half<2; half++){
    float o[32];
    #pragma unroll
    for (int j=0;j<32;j++) o[j] = b2[half*32 + j];
    #pragma unroll 4
    for (int k=0;k<64;k++) fma32(o, t[k], w2 + k*H + half*32);
    unsigned int u[16];
    #pragma unroll
    for (int j=0;j<16;j++) u[j] = pkh_(relu_(o[2*j]), relu_(o[2*j+1]));
    uint4* dp = (uint4*)(hbf + (size_t)v*H + half*32);
    #pragma unroll
    for (int j=0;j<4;j++) dp[j] = *(uint4*)&u[4*j];
  }
}

// ---------------- in-degree counts + per-edge rank ----------------
__global__ __launch_bounds__(256) void rank_kernel(const int* __restrict__ dst,
                                                   int* __restrict__ counts,
                                                   int* __restrict__ rank)
{
  int e = blockIdx.x*256 + threadIdx.x;
  if (e < NE) rank[e] = atomicAdd(&counts[dst[e]], 1);
}

// ---------------- scan phase 1 ----------------
__global__ __launch_bounds__(1024) void scan1_kernel(const int* __restrict__ counts,
                                                     int* __restrict__ row_excl,
                                                     int* __restrict__ part)
{
  __shared__ int buf[1024];
  int tid = threadIdx.x;
  int i = blockIdx.x*1024 + tid;
  int v = (i < NN) ? counts[i] : 0;
  buf[tid] = v;
  __syncthreads();
  for (int off=1; off<1024; off<<=1){
    int t = (tid >= off) ? buf[tid-off] : 0;
    __syncthreads();
    buf[tid] += t;
    __syncthreads();
  }
  if (i < NN) row_excl[i] = buf[tid] - v;
  if (tid == 1023) part[blockIdx.x] = buf[1023];
}

// ---------------- scan phase 2 ----------------
__global__ __launch_bounds__(128) void scan2_kernel(int* __restrict__ part, int nparts)
{
  __shared__ int buf[128];
  int tid = threadIdx.x;
  int v = (tid < nparts) ? part[tid] : 0;
  buf[tid] = v;
  __syncthreads();
  for (int off=1; off<128; off<<=1){
    int t = (tid >= off) ? buf[tid-off] : 0;
    __syncthreads();
    buf[tid] += t;
    __syncthreads();
  }
  if (tid < nparts) part[tid] = buf[tid] - v;
}

// ---------------- fill sorted src (no atomics; rank precomputed) ----------------
__global__ __launch_bounds__(256) void fill_kernel(
    const int* __restrict__ src, const int* __restrict__ dst,
    const int* __restrict__ row_excl, const int* __restrict__ part,
    const int* __restrict__ rank, int* __restrict__ ssrc)
{
  int e = blockIdx.x*256 + threadIdx.x;
  if (e >= NE) return;
  int d = dst[e];
  int p = row_excl[d] + part[d >> 10] + rank[e];
  ssrc[p] = src[e];
}

// ---------------- fill sorted dst coalesced from CSR ranges ----------------
__global__ __launch_bounds__(256) void dstfill_kernel(
    const int* __restrict__ counts, const int* __restrict__ row_excl,
    const int* __restrict__ part, int* __restrict__ sdst)
{
  int v = blockIdx.x*256 + threadIdx.x;
  if (v >= NN) return;
  int b = row_excl[v] + part[v >> 10];
  int cnt = counts[v];
  for (int i=0;i<cnt;i++) sdst[b+i] = v;
}

// ---------------- preswizzle ALL weights to fp16 MFMA B-fragment order -------------
// frag index within a K x N weight: idx = ((kb*4+quad)*N + col)*8 + j,  k = kb*32+quad*8+j
// layout (ushort elems): [0,24576) uw1p | [24576,36864) uw2p |
// [36864,61440) pprojp | [61440,65536) ow1p | [65536,77824) msgw2p   (all fp16)
__global__ __launch_bounds__(256) void prep_all_kernel(
    const float* __restrict__ uw1, const float* __restrict__ uw2,
    const float* __restrict__ mw1, const float* __restrict__ mw2,
    const float* __restrict__ ow1, unsigned short* __restrict__ wp)
{
  int i = blockIdx.x*256 + threadIdx.x;
  if (i >= 77824) return;
  float val;
  if (i < 24576){
    int l = i / 8192, r = i & 8191;
    int j = r & 7, col = (r >> 3) & 63, g = r >> 9;
    int k = (g >> 2)*32 + (g & 3)*8 + j;
    val = uw1[(size_t)l*8192 + k*64 + col];
  } else if (i < 36864){
    int t = i - 24576; int l = t / 4096, r = t & 4095;
    int j = r & 7, col = (r >> 3) & 63, g = r >> 9;
    int k = (g >> 2)*32 + (g & 3)*8 + j;
    val = uw2[(size_t)l*4096 + k*64 + col];
  } else if (i < 61440){
    int t = i - 36864; int l = t / 8192, r = t & 8191;
    int j = r & 7, col = (r >> 3) & 127, g = r >> 10;
    int k = (g >> 2)*32 + (g & 3)*8 + j;
    val = mw1[(size_t)l*8192 + ((col >> 6)*64 + k)*64 + (col & 63)];
  } else if (i < 65536){
    int r = i - 61440;
    int j = r & 7, col = (r >> 3) & 63, g = r >> 9;
    int k = (g >> 2)*32 + (g & 3)*8 + j;
    val = ow1[k*64 + col];
  } else {
    int t = i - 65536; int l = t / 4096, r = t & 4095;
    int j = r & 7, col = (r >> 3) & 63, g = r >> 9;
    int k = (g >> 2)*32 + (g & 3)*8 + j;
    val = mw2[(size_t)l*4096 + k*64 + col];
  }
  wp[i] = f2h_(val);
}

// ---------------- MFMA message kernel v10 (round-16 best): fp16 stores, simple walk,
// __launch_bounds__(MBT,4) — 40 VGPR spill-free, 4 blocks/CU ----------
__global__ __launch_bounds__(MBT, 4) void msg_mfma_kernel(
    const unsigned short* __restrict__ P,
    const unsigned short* __restrict__ w2p,
    const float* __restrict__ b2,
    const int* __restrict__ ssrc, const int* __restrict__ sdst,
    unsigned short* __restrict__ aggh,
    float* __restrict__ bval, int* __restrict__ bdst)
{
  __shared__ unsigned short mlds[64*MSTRIDE];
  __shared__ int2 sdl[EB];
  const int tid  = threadIdx.x;
  const int wave = tid >> 6, lane = tid & 63, quad = lane >> 4, c = lane & 15;

  // XCD-contiguous swizzle
  int bid = blockIdx.x;
  int ng = gridDim.x >> 3;
  int lb = (bid < (ng << 3)) ? ((bid & 7)*ng + (bid >> 3)) : bid;
  const int base = lb*EB;

  if (tid < EB){
    int p = base + tid;
    int sv = 0, dv = -1;
    if (p < NE){ sv = ssrc[p]; dv = sdst[p]; }
    sdl[tid] = make_int2(sv, dv);
  }

  // B fragments (fp16) + bias
  f16x8 bfr[4][2];
  #pragma unroll
  for (int n=0;n<4;n++)
    #pragma unroll
    for (int kb=0;kb<2;kb++)
      bfr[n][kb] = *(const f16x8*)(w2p + (((kb*4 + quad)*64 + n*16 + c) << 3));
  float bv[4];
  #pragma unroll
  for (int n=0;n<4;n++) bv[n] = b2[n*16 + c];

  __syncthreads();

  const int ebase = wave*32;
  #pragma unroll
  for (int t=0;t<2;t++){
    int2 sd = sdl[ebase + t*16 + c];
    int s = sd.x;
    int d = sd.y < 0 ? 0 : sd.y;
    const unsigned short* p1 = P + (size_t)s*128 + quad*8;
    const unsigned short* p2 = P + (size_t)d*128 + 64 + quad*8;
    f16x8 af[2];
    #pragma unroll
    for (int kb=0;kb<2;kb++){
      uint4 u1 = *(const uint4*)(p1 + kb*32);
      uint4 u2 = *(const uint4*)(p2 + kb*32);
      union { unsigned int u[4]; f16x8 v; } A;
      A.u[0] = addrelu2_(u1.x, u2.x);
      A.u[1] = addrelu2_(u1.y, u2.y);
      A.u[2] = addrelu2_(u1.z, u2.z);
      A.u[3] = addrelu2_(u1.w, u2.w);
      af[kb] = A.v;
    }

    f32x4 acc4[4];
    #pragma unroll
    for (int n=0;n<4;n++) acc4[n] = (f32x4){0.f, 0.f, 0.f, 0.f};
    #pragma unroll
    for (int n=0;n<4;n++){
      acc4[n] = __builtin_amdgcn_mfma_f32_16x16x32_f16(af[0], bfr[n][0], acc4[n], 0, 0, 0);
      acc4[n] = __builtin_amdgcn_mfma_f32_16x16x32_f16(af[1], bfr[n][1], acc4[n], 0, 0, 0);
    }

    int e0 = ebase + t*16 + quad*4;
    #pragma unroll
    for (int n=0;n<4;n++){
      int ch = n*16 + c;
      float v0 = relu_(acc4[n][0] + bv[n]);
      float v1 = relu_(acc4[n][1] + bv[n]);
      float v2 = relu_(acc4[n][2] + bv[n]);
      float v3 = relu_(acc4[n][3] + bv[n]);
      *(unsigned int*)&mlds[ch*MSTRIDE + e0]     = pkh_(v0, v1);
      *(unsigned int*)&mlds[ch*MSTRIDE + e0 + 2] = pkh_(v2, v3);
    }
  }
  __syncthreads();

  // ---- block-wide peek-ahead segmented reduce (single owner per run) ----
  // wave g owns runs STARTING in [g*32,(g+1)*32); SIMPLE accumulation walk.
  {
    const int g = wave;
    const int ch = lane;
    int r = g*32;
    if (g > 0){
      int prev = sdl[r-1].y;
      while (r < EB && sdl[r].y == prev) r++;
    }
    while (r < EB){
      int runstart = r;
      if (runstart >= (g+1)*32) break;
      int cur = sdl[r].y;
      float s2 = 0.f;
      while (r < EB && sdl[r].y == cur){
        s2 += h2f_(mlds[ch*MSTRIDE + r]);
        r++;
      }
      if (cur >= 0){
        bool headB = (runstart == 0);
        bool tailB = (r == EB);
        if (headB){
          bval[(size_t)(2*lb)*64 + ch] = s2;
          if (ch == 0) bdst[2*lb] = cur;
          if (tailB){
            bval[(size_t)(2*lb+1)*64 + ch] = 0.f;   // contiguity filler
            if (ch == 0) bdst[2*lb+1] = cur;
          }
        } else if (tailB){
          bval[(size_t)(2*lb+1)*64 + ch] = s2;
          if (ch == 0) bdst[2*lb+1] = cur;
        } else {
          aggh[(size_t)cur*H + ch] = f2h_(s2);
        }
      }
    }
  }
}

// ---------------- second-level boundary merge: zero atomics, plain stores ----------
__global__ __launch_bounds__(256) void bnd_fixup_kernel(
    const int* __restrict__ bdst, const float* __restrict__ bval,
    unsigned short* __restrict__ aggh, int nbnd)
{
  const int wave = threadIdx.x >> 6, ch = threadIdx.x & 63;
  int g = blockIdx.x*4 + wave;
  int r0 = g*64;
  if (r0 >= nbnd) return;
  int r = r0;
  if (r0 > 0){
    int prev = bdst[r0-1];
    while (r < nbnd && bdst[r] == prev) r++;
  }
  int rlim = r0 + 64;
  while (r < nbnd){
    int runstart = r;
    if (runstart >= rlim) break;
    int cur = bdst[r];
    float s = 0.f;
    while (r < nbnd && bdst[r] == cur){
      s += bval[(size_t)r*64 + ch];
      r++;
    }
    if (cur >= 0) aggh[(size_t)cur*H + ch] = f2h_(s);
  }
}

// ---------------- fused node-side layer kernel (fp16 MFMA, fp16 agg in) -------------
// mode 0 (l=0,1): h' = relu-MLP2([h||agg/deg]) -> hout(fp16) ; P_next = h'@W3 (+b3 top) -> Pout
// mode 1 (l=2):   h' as above; out = 2pi*sigmoid(relu(h'@ow1+b3)@ow2+ob2) -> outp
// mode 2 (pproj only): P = hbf@W3 (+b3 top) -> Pout
// Zero-degree nodes: agg never written (no memset) -> masked via invd=0.
__global__ __launch_bounds__(256) void node_fused_kernel(
    const unsigned short* __restrict__ hbf,
    const unsigned short* __restrict__ aggh, const int* __restrict__ counts,
    const unsigned short* __restrict__ uw1p, const float* __restrict__ ub1,
    const unsigned short* __restrict__ uw2p, const float* __restrict__ ub2,
    const unsigned short* __restrict__ w3p,  const float* __restrict__ b3,
    const float* __restrict__ ow2, const float* __restrict__ ob2,
    unsigned short* __restrict__ hout,
    unsigned short* __restrict__ Pout,
    float* __restrict__ outp,
    int mode)
{
  __shared__ __align__(16) unsigned short act[64*72];
  __shared__ __align__(16) unsigned short pst[64*136];
  const int tid = threadIdx.x, wave = tid >> 6, lane = tid & 63;
  const int quad = lane >> 4, c = lane & 15;
  const int vb = blockIdx.x*64;
  int myv = vb + wave*16 + c;
  int vld = myv < NN ? myv : NN-1;

  if (mode != 2){
    int cntv = counts[vld];
    float invf = (cntv > 0) ? (1.0f / (float)cntv) : 0.0f;   // masks unwritten agg
    f16x2 invd2; invd2[0] = (_Float16)invf; invd2[1] = (_Float16)invf;
    f16x8 a1[4];
    a1[0] = *(const f16x8*)(hbf + (size_t)vld*H + quad*8);
    a1[1] = *(const f16x8*)(hbf + (size_t)vld*H + 32 + quad*8);
    #pragma unroll
    for (int kb2=0; kb2<2; kb2++){
      uint4 u = *(const uint4*)(aggh + (size_t)vld*H + kb2*32 + quad*8);
      union { unsigned int u[4]; f16x8 v; } A;
      A.u[0] = mulpk_(u.x, invd2);
      A.u[1] = mulpk_(u.y, invd2);
      A.u[2] = mulpk_(u.z, invd2);
      A.u[3] = mulpk_(u.w, invd2);
      a1[2+kb2] = A.v;
    }
    f32x4 acc1[4];
    #pragma unroll
    for (int n=0;n<4;n++) acc1[n] = (f32x4){0.f,0.f,0.f,0.f};
    #pragma unroll
    for (int n=0;n<4;n++){
      #pragma unroll
      for (int kb=0;kb<4;kb++){
        f16x8 b = *(const f16x8*)(uw1p + (((kb*4 + quad)*64 + n*16 + c) << 3));
        acc1[n] = __builtin_amdgcn_mfma_f32_16x16x32_f16(a1[kb], b, acc1[n], 0, 0, 0);
      }
    }
    #pragma unroll
    for (int n=0;n<4;n++){
      float bb = ub1[n*16 + c];
      #pragma unroll
      for (int r=0;r<4;r++)
        act[(wave*16 + quad*4 + r)*72 + n*16 + c] = f2h_(relu_(acc1[n][r] + bb));
    }

    f16x8 a2[2];
    a2[0] = *(const f16x8*)(act + (wave*16 + c)*72 + quad*8);
    a2[1] = *(const f16x8*)(act + (wave*16 + c)*72 + 32 + quad*8);
    f32x4 acc2[4];
    #pragma unroll
    for (int n=0;n<4;n++) acc2[n] = (f32x4){0.f,0.f,0.f,0.f};
    #pragma unroll
    for (int n=0;n<4;n++){
      #pragma unroll
      for (int kb=0;kb<2;kb++){
        f16x8 b = *(const f16x8*)(uw2p + (((kb*4 + quad)*64 + n*16 + c) << 3));
        acc2[n] = __builtin_amdgcn_mfma_f32_16x16x32_f16(a2[kb], b, acc2[n], 0, 0, 0);
      }
    }
    #pragma unroll
    for (int n=0;n<4;n++){
      float bb = ub2[n*16 + c];
      #pragma unroll
      for (int r=0;r<4;r++)
        act[(wave*16 + quad*4 + r)*72 + n*16 + c] = f2h_(relu_(acc2[n][r] + bb));
    }
  }

  f16x8 a3[2];
  if (mode == 2){
    a3[0] = *(const f16x8*)(hbf + (size_t)vld*H + quad*8);
    a3[1] = *(const f16x8*)(hbf + (size_t)vld*H + 32 + quad*8);
  } else {
    a3[0] = *(const f16x8*)(act + (wave*16 + c)*72 + quad*8);
    a3[1] = *(const f16x8*)(act + (wave*16 + c)*72 + 32 + quad*8);
  }

  if (mode == 1){
    f32x4 acc3[4];
    #pragma unroll
    for (int n=0;n<4;n++) acc3[n] = (f32x4){0.f,0.f,0.f,0.f};
    #pragma unroll
    for (int n=0;n<4;n++){
      #pragma unroll
      for (int kb=0;kb<2;kb++){
        f16x8 b = *(const f16x8*)(w3p + (((kb*4 + quad)*64 + n*16 + c) << 3));
        acc3[n] = __builtin_amdgcn_mfma_f32_16x16x32_f16(a3[kb], b, acc3[n], 0, 0, 0);
      }
    }
    #pragma unroll
    for (int n=0;n<4;n++){
      float bb = b3[n*16 + c];
      #pragma unroll
      for (int r=0;r<4;r++)
        act[(wave*16 + quad*4 + r)*72 + n*16 + c] = f2h_(relu_(acc3[n][r] + bb));
    }
  } else {
    f32x4 acc3[8];
    #pragma unroll
    for (int n=0;n<8;n++) acc3[n] = (f32x4){0.f,0.f,0.f,0.f};
    #pragma unroll
    for (int n=0;n<8;n++){
      #pragma unroll
      for (int kb=0;kb<2;kb++){
        f16x8 b = *(const f16x8*)(w3p + (((kb*4 + quad)*128 + n*16 + c) << 3));
        acc3[n] = __builtin_amdgcn_mfma_f32_16x16x32_f16(a3[kb], b, acc3[n], 0, 0, 0);
      }
    }
    #pragma unroll
    for (int n=0;n<8;n++){
      int ch = n*16 + c;
      float bb = (ch >= 64) ? b3[ch - 64] : 0.0f;
      #pragma unroll
      for (int r=0;r<4;r++)
        pst[(wave*16 + quad*4 + r)*136 + ch] = f2h_(acc3[n][r] + bb);
    }
  }

  __syncthreads();

  if (mode == 0){
    #pragma unroll
    for (int rr=0; rr<2; rr++){
      int idx = tid + rr*256;
      int node = idx >> 3, ko = (idx & 7)*8;
      int v = vb + node;
      if (v < NN) *(uint4*)(hout + (size_t)v*H + ko) = *(const uint4*)(act + node*72 + ko);
    }
  }
  if (mode == 0 || mode == 2){
    #pragma unroll
    for (int rr=0; rr<4; rr++){
      int idx = tid + rr*256;
      int node = idx >> 4, cho = (idx & 15)*8;
      int v = vb + node;
      if (v < NN) *(uint4*)(Pout + (size_t)v*128 + cho) = *(const uint4*)(pst + node*136 + cho);
    }
  }
  if (mode == 1){
    if (tid < 192){
      int node = tid / 3;
      int v = vb + node;
      if (v < NN){
        int cm = tid - node*3;
        float s = ob2[cm];
        #pragma unroll 8
        for (int k=0;k<64;k++)
          s = fmaf(h2f_(act[node*72 + k]), ow2[k*3 + cm], s);
        outp[(size_t)v*3 + cm] = 6.283185307179586f / (1.0f + __expf(-s));
      }
    }
  }
}

// ================= legacy fallback kernels (known correct; small ws) =================
__global__ __launch_bounds__(256) void enc_kernel_legacy(
    const float* __restrict__ x,
    const float* __restrict__ w1, const float* __restrict__ b1,
    const float* __restrict__ w2, const float* __restrict__ b2,
    float* __restrict__ h)
{
  int v = blockIdx.x*256 + threadIdx.x;
  if (v >= NN) return;
  float in0[5];
  #pragma unroll
  for (int k=0;k<5;k++) in0[k] = x[v*5+k];
  float hid[H];
  #pragma unroll
  for (int j=0;j<H;j++) hid[j] = b1[j];
  #pragma unroll
  for (int k=0;k<5;k++){
    #pragma unroll
    for (int j=0;j<H;j++) hid[j] = fmaf(in0[k], w1[k*H+j], hid[j]);
  }
  float o[H];
  #pragma unroll
  for (int j=0;j<H;j++) o[j] = b2[j];
  #pragma unroll
  for (int k=0;k<H;k++){
    float hk = relu_(hid[k]);
    #pragma unroll
    for (int j=0;j<H;j++) o[j] = fmaf(hk, w2[k*H+j], o[j]);
  }
  float4* hw = (float4*)(h + (size_t)v*H);
  #pragma unroll
  for (int j4=0;j4<H/4;j4++){
    float4 t;
    t.x = relu_(o[4*j4+0]); t.y = relu_(o[4*j4+1]);
    t.z = relu_(o[4*j4+2]); t.w = relu_(o[4*j4+3]);
    hw[j4] = t;
  }
}

__global__ __launch_bounds__(256) void msg_kernel_atomic(
    const float* __restrict__ h,
    const int* __restrict__ src, const int* __restrict__ dst,
    const float* __restrict__ w1, const float* __restrict__ b1,
    const float* __restrict__ w2, const float* __restrict__ b2,
    float* __restrict__ agg)
{
  int e = blockIdx.x*256 + threadIdx.x;
  if (e >= NE) return;
  int s = src[e], d = dst[e];
  const float4* hs = (const float4*)(h + (size_t)s*H);
  const float4* hd = (const float4*)(h + (size_t)d*H);
  float hid[H];
  #pragma unroll
  for (int j=0;j<H;j++) hid[j] = b1[j];
  #pragma unroll 4
  for (int k4=0;k4<16;k4++){
    float4 a = hs[k4];
    const float* wr = w1 + (size_t)(4*k4)*H;
    #pragma unroll
    for (int j=0;j<H;j++) hid[j] = fmaf(a.x, wr[j], hid[j]);
    #pragma unroll
    for (int j=0;j<H;j++) hid[j] = fmaf(a.y, wr[H+j], hid[j]);
    #pragma unroll
    for (int j=0;j<H;j++) hid[j] = fmaf(a.z, wr[2*H+j], hid[j]);
    #pragma unroll
    for (int j=0;j<H;j++) hid[j] = fmaf(a.w, wr[3*H+j], hid[j]);
  }
  #pragma unroll 4
  for (int k4=0;k4<16;k4++){
    float4 a = hd[k4];
    const float* wr = w1 + (size_t)(64 + 4*k4)*H;
    #pragma unroll
    for (int j=0;j<H;j++) hid[j] = fmaf(a.x, wr[j], hid[j]);
    #pragma unroll
    for (int j=0;j<H;j++) hid[j] = fmaf(a.y, wr[H+j], hid[j]);
    #pragma unroll
    for (int j=0;j<H;j++) hid[j] = fmaf(a.z, wr[2*H+j], hid[j]);
    #pragma unroll
    for (int j=0;j<H;j++) hid[j] = fmaf(a.w, wr[3*H+j], hid[j]);
  }
  float o[H];
  #pragma unroll
  for (int j=0;j<H;j++) o[j] = b2[j];
  #pragma unroll
  for (int k=0;k<H;k++){
    float hk = relu_(hid[k]);
    #pragma unroll
    for (int j=0;j<H;j++) o[j] = fmaf(hk, w2[k*H+j], o[j]);
  }
  float* arow = agg + (size_t)d*H;
  #pragma unroll
  for (int j=0;j<H;j++) atomicAdd(arow + j, relu_(o[j]));
}

__global__ __launch_bounds__(256) void div_kernel(float* __restrict__ agg,
                                                  const int* __restrict__ counts)
{
  int i = blockIdx.x*256 + threadIdx.x;
  if (i >= NN*H/4) return;
  int v = i / (H/4);
  float invd = 1.0f / fmaxf((float)counts[v], 1.0f);
  float4* a = (float4*)agg + i;
  float4 t = *a;
  t.x *= invd; t.y *= invd; t.z *= invd; t.w *= invd;
  *a = t;
}

__global__ __launch_bounds__(256) void upd_kernel_legacy(
    float* __restrict__ h, const float* __restrict__ agg,
    const float* __restrict__ w1, const float* __restrict__ b1,
    const float* __restrict__ w2, const float* __restrict__ b2)
{
  int v = blockIdx.x*256 + threadIdx.x;
  if (v >= NN) return;
  const float4* hv = (const float4*)(h + (size_t)v*H);
  const float4* av = (const float4*)(agg + (size_t)v*H);
  float hid[H];
  #pragma unroll
  for (int j=0;j<H;j++) hid[j] = b1[j];
  #pragma unroll 4
  for (int k4=0;k4<16;k4++){
    float4 a = hv[k4];
    const float* wr = w1 + (size_t)(4*k4)*H;
    #pragma unroll
    for (int j=0;j<H;j++) hid[j] = fmaf(a.x, wr[j], hid[j]);
    #pragma unroll
    for (int j=0;j<H;j++) hid[j] = fmaf(a.y, wr[H+j], hid[j]);
    #pragma unroll
    for (int j=0;j<H;j++) hid[j] = fmaf(a.z, wr[2*H+j], hid[j]);
    #pragma unroll
    for (int j=0;j<H;j++) hid[j] = fmaf(a.w, wr[3*H+j], hid[j]);
  }
  #pragma unroll 4
  for (int k4=0;k4<16;k4++){
    float4 a = av[k4];
    const float* wr = w1 + (size_t)(64 + 4*k4)*H;
    #pragma unroll
    for (int j=0;j<H;j++) hid[j] = fmaf(a.x, wr[j], hid[j]);
    #pragma unroll
    for (int j=0;j<H;j++) hid[j] = fmaf(a.y, wr[H+j], hid[j]);
    #pragma unroll
    for (int j=0;j<H;j++) hid[j] = fmaf(a.z, wr[2*H+j], hid[j]);
    #pragma unroll
    for (int j=0;j<H;j++) hid[j] = fmaf(a.w, wr[3*H+j], hid[j]);
  }
  float o[H];
  #pragma unroll
  for (int j=0;j<H;j++) o[j] = b2[j];
  #pragma unroll
  for (int k=0;k<H;k++){
    float hk = relu_(hid[k]);
    #pragma unroll
    for (int j=0;j<H;j++) o[j] = fmaf(hk, w2[k*H+j], o[j]);
  }
  float4* hw = (float4*)(h + (size_t)v*H);
  #pragma unroll
  for (int j4=0;j4<H/4;j4++){
    float4 t;
    t.x = relu_(o[4*j4+0]); t.y = relu_(o[4*j4+1]);
    t.z = relu_(o[4*j4+2]); t.w = relu_(o[4*j4+3]);
    hw[j4] = t;
  }
}

__global__ __launch_bounds__(256) void out_kernel2(
    const float* __restrict__ h,
    const float* __restrict__ w1, const float* __restrict__ b1,
    const float* __restrict__ w2, const float* __restrict__ b2,
    float* __restrict__ out)
{
  int v = blockIdx.x*256 + threadIdx.x;
  if (v >= NN) return;
  const float4* hv = (const float4*)(h + (size_t)v*H);
  float pr[3] = { b2[0], b2[1], b2[2] };
  #pragma unroll 1
  for (int half=0; half<2; half++){
    float o[32];
    #pragma unroll
    for (int j=0;j<32;j++) o[j] = b1[half*32 + j];
    #pragma unroll 4
    for (int k4=0;k4<16;k4++){
      float4 a = hv[k4];
      const float* wr = w1 + (4*k4)*H + half*32;
      fma32(o, a.x, wr); fma32(o, a.y, wr+H); fma32(o, a.z, wr+2*H); fma32(o, a.w, wr+3*H);
    }
    #pragma unroll
    for (int j=0;j<32;j++){
      float hk = relu_(o[j]);
      int k = half*32 + j;
      pr[0] = fmaf(hk, w2[k*3+0], pr[0]);
      pr[1] = fmaf(hk, w2[k*3+1], pr[1]);
      pr[2] = fmaf(hk, w2[k*3+2], pr[2]);
    }
  }
  #pragma unroll
  for (int c=0;c<3;c++)
    out[(size_t)v*3 + c] = 6.283185307179586f / (1.0f + __expf(-pr[c]));
}

// =====================================================================

extern "C" void kernel_launch(void* const* d_in, const int* in_sizes, int n_in,
                              void* d_out, int out_size, void* d_ws, size_t ws_size,
                              hipStream_t stream)
{
  const float* x      = (const float*)d_in[0];
  const int*   ei     = (const int*)  d_in[1];
  const float* enc_w1 = (const float*)d_in[2];
  const float* enc_b1 = (const float*)d_in[3];
  const float* enc_w2 = (const float*)d_in[4];
  const float* enc_b2 = (const float*)d_in[5];
  const float* msg_w1 = (const float*)d_in[6];
  const float* msg_b1 = (const float*)d_in[7];
  const float* msg_w2 = (const float*)d_in[8];
  const float* msg_b2 = (const float*)d_in[9];
  const float* upd_w1 = (const float*)d_in[10];
  const float* upd_b1 = (const float*)d_in[11];
  const float* upd_w2 = (const float*)d_in[12];
  const float* upd_b2 = (const float*)d_in[13];
  const float* out_w1 = (const float*)d_in[14];
  const float* out_b1 = (const float*)d_in[15];
  const float* out_w2 = (const float*)d_in[16];
  const float* out_b2 = (const float*)d_in[17];
  float* out = (float*)d_out;

  const int* srcp = ei;
  const int* dstp = ei + NE;

  const int nodeBlocks  = (NN + 255)/256;
  const int edgeBlocks  = (NE + 255)/256;
  const int msgBlocks   = (NE + EB - 1)/EB;          // 7813
  const int nbnd        = 2*msgBlocks;               // 15626
  const int fixBlocks   = ((nbnd + 63)/64 + 3)/4;    // 62
  const int scanBlocks  = (NN + 1023)/1024;
  const int fusedBlocks = (NN + 63)/64;              // 1563

  // ---- workspace layout ----
  char* wp_ = (char*)d_ws;
  auto take = [&wp_](size_t bytes) -> char* {
    char* r = wp_;
    wp_ += (bytes + 255) & ~(size_t)255;
    return r;
  };
  unsigned short* hbf = (unsigned short*)take((size_t)NN*H*sizeof(unsigned short)); // 12.8 MB fp16
  unsigned short* P   = (unsigned short*)take((size_t)NN*128*sizeof(unsigned short)); // 25.6 MB fp16
  unsigned short* aggh= (unsigned short*)take((size_t)NN*H*sizeof(unsigned short)); // 12.8 MB fp16
  int* counts         = (int*)take((size_t)NN*sizeof(int));
  int* row_excl       = (int*)take((size_t)NN*sizeof(int));
  int* part           = (int*)take(1024);
  int* rank           = (int*)take((size_t)NE*sizeof(int));                        // 4 MB
  int* ssrc           = (int*)take((size_t)NE*sizeof(int));                        // 4 MB
  int* sdst           = (int*)take((size_t)NE*sizeof(int));                        // 4 MB
  float* bval         = (float*)take((size_t)nbnd*64*sizeof(float));               // 4 MB
  int* bdst           = (int*)take((size_t)nbnd*sizeof(int));
  unsigned short* wpz = (unsigned short*)take((size_t)77824*sizeof(unsigned short));
  size_t need = (size_t)(wp_ - (char*)d_ws);

  // preswizzled-weight offsets (ushort elements)
  const size_t UW1 = 0, UW2 = 24576, PPJ = 36864, OW1 = 61440, MW2 = 65536;

  if (ws_size >= need) {
    (void)hipMemsetAsync(counts, 0, NN*sizeof(int), stream);
    (void)hipMemsetAsync(bdst, 0xFF, nbnd*sizeof(int), stream);   // dst = -1 sentinel

    enc_full_kernel<<<nodeBlocks, 256, 0, stream>>>(x, enc_w1, enc_b1, enc_w2, enc_b2, hbf);

    rank_kernel<<<edgeBlocks, 256, 0, stream>>>(dstp, counts, rank);
    scan1_kernel<<<scanBlocks, 1024, 0, stream>>>(counts, row_excl, part);
    scan2_kernel<<<1, 128, 0, stream>>>(part, scanBlocks);
    fill_kernel<<<edgeBlocks, 256, 0, stream>>>(srcp, dstp, row_excl, part, rank, ssrc);
    dstfill_kernel<<<nodeBlocks, 256, 0, stream>>>(counts, row_excl, part, sdst);
    prep_all_kernel<<<(77824 + 255)/256, 256, 0, stream>>>(upd_w1, upd_w2, msg_w1, msg_w2, out_w1, wpz);

    // layer-0 P projection (mode 2)
    node_fused_kernel<<<fusedBlocks, 256, 0, stream>>>(
        hbf, aggh, counts,
        nullptr, nullptr, nullptr, nullptr,
        wpz + PPJ, msg_b1, nullptr, nullptr,
        nullptr, P, nullptr, 2);

    for (int l=0; l<3; l++){
      msg_mfma_kernel<<<msgBlocks, MBT, 0, stream>>>(P, wpz + MW2 + (size_t)l*4096,
          msg_b2 + (size_t)l*H, ssrc, sdst, aggh, bval, bdst);
      bnd_fixup_kernel<<<fixBlocks, 256, 0, stream>>>(bdst, bval, aggh, nbnd);
      if (l < 2){
        node_fused_kernel<<<fusedBlocks, 256, 0, stream>>>(
            hbf, aggh, counts,
            wpz + UW1 + (size_t)l*8192, upd_b1 + (size_t)l*H,
            wpz + UW2 + (size_t)l*4096, upd_b2 + (size_t)l*H,
            wpz + PPJ + (size_t)(l+1)*8192, msg_b1 + (size_t)(l+1)*H,
            nullptr, nullptr,
            hbf, P, nullptr, 0);
      } else {
        node_fused_kernel<<<fusedBlocks, 256, 0, stream>>>(
            hbf, aggh, counts,
            wpz + UW1 + (size_t)l*8192, upd_b1 + (size_t)l*H,
            wpz + UW2 + (size_t)l*4096, upd_b2 + (size_t)l*H,
            wpz + OW1, out_b1,
            out_w2, out_b2,
            nullptr, nullptr, out, 1);
      }
    }
  } else {
    // ======== fallback: legacy atomic path (fits in ~52 MB) ========
    char* fp = (char*)d_ws;
    float* fh   = (float*)fp;  fp += (size_t)NN*H*sizeof(float);
    float* fagg = (float*)fp;  fp += (size_t)NN*H*sizeof(float);
    int* fcnt   = (int*)fp;

    (void)hipMemsetAsync(fcnt, 0, NN*sizeof(int), stream);
    enc_kernel_legacy<<<nodeBlocks, 256, 0, stream>>>(x, enc_w1, enc_b1, enc_w2, enc_b2, fh);
    rank_kernel<<<edgeBlocks, 256, 0, stream>>>(dstp, fcnt, (int*)(fcnt + NN));
    for (int l=0; l<3; l++){
      (void)hipMemsetAsync(fagg, 0, (size_t)NN*H*sizeof(float), stream);
      msg_kernel_atomic<<<edgeBlocks, 256, 0, stream>>>(fh, srcp, dstp,
          msg_w1 + (size_t)l*128*H, msg_b1 + (size_t)l*H,
          msg_w2 + (size_t)l*H*H,   msg_b2 + (size_t)l*H, fagg);
      div_kernel<<<(NN*H/4 + 255)/256, 256, 0, stream>>>(fagg, fcnt);
      upd_kernel_legacy<<<nodeBlocks, 256, 0, stream>>>(fh, fagg,
          upd_w1 + (size_t)l*128*H, upd_b1 + (size_t)l*H,
          upd_w2 + (size_t)l*H*H,   upd_b2 + (size_t)l*H);
    }
    out_kernel2<<<nodeBlocks, 256, 0, stream>>>(fh, out_w1, out_b1, out_w2, out_b2, out);
  }
}